// Round 5
// baseline (947.846 us; speedup 1.0000x reference)
//
#include <hip/hip_runtime.h>

#define F 128            // feature dim (HID == NF == 128)

typedef __attribute__((ext_vector_type(8))) __bf16 bf16x8;
typedef __attribute__((ext_vector_type(4))) float floatx4;

// shifted softplus: softplus(x) - log(2) == log((1+e^x)/2)
__device__ __forceinline__ float ssp(float x) {
    return __logf(fmaf(0.5f, __expf(x), 0.5f));
}

__device__ __forceinline__ floatx4 mfma_bf16(bf16x8 a, bf16x8 b, floatx4 c) {
    return __builtin_amdgcn_mfma_f32_16x16x32_bf16(a, b, c, 0, 0, 0);
}

// ---------------------------------------------------------------------------
// prep: weights f32 -> bf16(hi)+bf16(lo); also zero the histogram counters
// ---------------------------------------------------------------------------
__global__ void prep_kernel(const float* __restrict__ fc1w,
                            const float* __restrict__ fw1,
                            const float* __restrict__ fw2,
                            const float* __restrict__ sw1,
                            const float* __restrict__ sw2,
                            __bf16* __restrict__ fc1h, __bf16* __restrict__ fc1l,
                            __bf16* __restrict__ fw1h, __bf16* __restrict__ fw2h,
                            __bf16* __restrict__ sw1h, __bf16* __restrict__ sw1l,
                            __bf16* __restrict__ sw2h, __bf16* __restrict__ sw2l,
                            int* __restrict__ cnt, int N)
{
    int i = blockIdx.x * blockDim.x + threadIdx.x;
    for (int j = i; j < N; j += gridDim.x * blockDim.x) cnt[j] = 0;
    if (i >= F * F) return;
    float v; __bf16 h;
    v = fc1w[i]; h = (__bf16)v; fc1h[i] = h; fc1l[i] = (__bf16)(v - (float)h);
    v = sw1[i];  h = (__bf16)v; sw1h[i] = h; sw1l[i] = (__bf16)(v - (float)h);
    v = sw2[i];  h = (__bf16)v; sw2h[i] = h; sw2l[i] = (__bf16)(v - (float)h);
    fw1h[i] = (__bf16)fw1[i];
    fw2h[i] = (__bf16)fw2[i];
}

// ---------------------------------------------------------------------------
// CSR build: histogram of dst -> exclusive scan -> cursor scatter.
// perm[slot] = original edge id; ssrc/sdst = src/dst per sorted slot.
// ---------------------------------------------------------------------------
__global__ __launch_bounds__(256) void hist_kernel(const int* __restrict__ eidx,
                                                   int* __restrict__ cnt, int E)
{
    int i = blockIdx.x * 256 + threadIdx.x;
    if (i < E) atomicAdd(&cnt[eidx[E + i]], 1);
}

__global__ __launch_bounds__(1024) void scan1_kernel(int* __restrict__ cnt,
                                                     int* __restrict__ bsums, int N)
{
    __shared__ int sd[1024];
    const int t = threadIdx.x;
    const int i = blockIdx.x * 1024 + t;
    int v = (i < N) ? cnt[i] : 0;
    sd[t] = v;
    __syncthreads();
    for (int off = 1; off < 1024; off <<= 1) {
        int add = (t >= off) ? sd[t - off] : 0;
        __syncthreads();
        sd[t] += add;
        __syncthreads();
    }
    if (i < N) cnt[i] = sd[t] - v;          // exclusive
    if (t == 1023) bsums[blockIdx.x] = sd[t];
}

__global__ void scan2_kernel(int* __restrict__ bsums, int nb)
{
    const int lane = threadIdx.x & 63;
    int v = (lane < nb) ? bsums[lane] : 0;
    int acc = v;
    #pragma unroll
    for (int off = 1; off < 64; off <<= 1) {
        int t = __shfl_up(acc, off);
        if (lane >= off) acc += t;
    }
    if (lane < nb) bsums[lane] = acc - v;   // exclusive
}

__global__ __launch_bounds__(1024) void scan3_kernel(int* __restrict__ cnt,
                                                     const int* __restrict__ bsums, int N)
{
    int i = blockIdx.x * 1024 + threadIdx.x;
    if (i < N) cnt[i] += bsums[blockIdx.x];
}

__global__ __launch_bounds__(256) void scatter_kernel(const int* __restrict__ eidx,
                                                      int* __restrict__ cursor,
                                                      int* __restrict__ perm,
                                                      int* __restrict__ ssrc,
                                                      int* __restrict__ sdst, int E)
{
    int i = blockIdx.x * 256 + threadIdx.x;
    if (i < E) {
        int d = eidx[E + i];
        int slot = atomicAdd(&cursor[d], 1);
        perm[slot] = i;
        ssrc[slot] = eidx[i];
        sdst[slot] = d;
    }
}

// ---------------------------------------------------------------------------
// y = x @ fc1_w.T   (split bf16, 3-term MFMA -> ~f32 exact)
// 32 rows/block, wave (g,c) owns rows g*16.. x cols c*64..; batched B-frags.
// No LDS. Small footprint -> high occupancy.
// ---------------------------------------------------------------------------
__global__ __launch_bounds__(256, 5) void fc1_kernel(
    const float* __restrict__ x, const __bf16* __restrict__ wh,
    const __bf16* __restrict__ wl, float* __restrict__ y, int M)
{
    const int tid = threadIdx.x;
    const int wv = tid >> 6, lane = tid & 63;
    const int m16 = lane & 15, q = lane >> 4;
    const int g = wv & 1, c = wv >> 1;
    const int rowA0 = blockIdx.x * 32 + g * 16 + m16;
    const int rowA = rowA0 < M ? rowA0 : M - 1;

    floatx4 acc[4] = {};
    #pragma unroll
    for (int ks = 0; ks < 4; ++ks) {
        const int kb = ks * 32 + q * 8;
        const float4* p = (const float4*)(x + (size_t)rowA * F + kb);
        float4 a0 = p[0], a1 = p[1];
        float fv[8] = {a0.x, a0.y, a0.z, a0.w, a1.x, a1.y, a1.z, a1.w};
        bf16x8 ah, al;
        #pragma unroll
        for (int i = 0; i < 8; ++i) {
            __bf16 h = (__bf16)fv[i];
            ah[i] = h; al[i] = (__bf16)(fv[i] - (float)h);
        }
        bf16x8 bH[4], bL[4];
        #pragma unroll
        for (int nt = 0; nt < 4; ++nt) {
            const size_t wo = (size_t)(c * 64 + nt * 16 + m16) * F + kb;
            bH[nt] = *(const bf16x8*)(wh + wo);
            bL[nt] = *(const bf16x8*)(wl + wo);
        }
        #pragma unroll
        for (int nt = 0; nt < 4; ++nt) {
            acc[nt] = mfma_bf16(ah, bH[nt], acc[nt]);
            acc[nt] = mfma_bf16(al, bH[nt], acc[nt]);
            acc[nt] = mfma_bf16(ah, bL[nt], acc[nt]);
        }
    }
    const int rowD0 = blockIdx.x * 32 + g * 16 + q * 4;
    #pragma unroll
    for (int nt = 0; nt < 4; ++nt) {
        const int col = c * 64 + nt * 16 + m16;
        #pragma unroll
        for (int r = 0; r < 4; ++r) {
            const int row = rowD0 + r;
            if (row < M) y[(size_t)row * F + col] = acc[nt][r];
        }
    }
}

// ---------------------------------------------------------------------------
// FUSED edge kernel over dst-SORTED slots:
//   W = ssp(ssp(ea[perm]@f_w1.T+b1)@f_w2.T+b2)   (W stays in f32 registers)
//   agg[dst] += y[src] * W   (run-merged atomics, dst-sorted)
// 64 slots/block, 4 waves, wave owns 16 rows x 128 cols.
// Small footprint (acc[8]=32 acc-regs, bF[8]=32) -> 4-5 waves/SIMD.
// ---------------------------------------------------------------------------
__global__ __launch_bounds__(256, 4) void edge_kernel(
    const float* __restrict__ edge_attr,
    const int* __restrict__ perm,
    const int* __restrict__ ssrc,
    const int* __restrict__ sdst,
    const float* __restrict__ fb1, const float* __restrict__ fb2,
    const __bf16* __restrict__ fw1, const __bf16* __restrict__ fw2,
    const float* __restrict__ y,
    float* __restrict__ agg, int E)
{
    __shared__ __align__(16) __bf16 h1s[4][16][136];

    const int tid = threadIdx.x;
    const int wv = tid >> 6, lane = tid & 63;
    const int m16 = lane & 15, q = lane >> 4;
    const int s0 = blockIdx.x * 64 + wv * 16;     // wave's first sorted slot
    __bf16 (*h1)[136] = h1s[wv];

    const int sA0 = s0 + m16;
    const int sA = sA0 < E ? sA0 : E - 1;
    const int eA = perm[sA];                       // original edge id (A-row)

    // ---- stage 1: h1 = ssp(ea @ f_w1.T + b1) ----
    floatx4 acc[8] = {};
    #pragma unroll
    for (int ks = 0; ks < 4; ++ks) {
        const int kb = ks * 32 + q * 8;
        const float4* pa = (const float4*)(edge_attr + (size_t)eA * F + kb);
        float4 a0 = pa[0], a1 = pa[1];
        float fv[8] = {a0.x, a0.y, a0.z, a0.w, a1.x, a1.y, a1.z, a1.w};
        bf16x8 aF;
        #pragma unroll
        for (int i = 0; i < 8; ++i) aF[i] = (__bf16)fv[i];
        bf16x8 bF[8];
        #pragma unroll
        for (int nt = 0; nt < 8; ++nt)
            bF[nt] = *(const bf16x8*)(fw1 + (size_t)(nt * 16 + m16) * F + kb);
        #pragma unroll
        for (int nt = 0; nt < 8; ++nt)
            acc[nt] = mfma_bf16(aF, bF[nt], acc[nt]);
    }
    #pragma unroll
    for (int nt = 0; nt < 8; ++nt) {
        const int col = nt * 16 + m16;
        const float b = fb1[col];
        #pragma unroll
        for (int r = 0; r < 4; ++r)
            h1[q * 4 + r][col] = (__bf16)ssp(acc[nt][r] + b);
    }
    __syncthreads();

    // ---- stage 2: W = ssp(h1 @ f_w2.T + b2) ----
    floatx4 zero = {};
    #pragma unroll
    for (int nt = 0; nt < 8; ++nt) acc[nt] = zero;
    #pragma unroll
    for (int ks = 0; ks < 4; ++ks) {
        const int kb = ks * 32 + q * 8;
        bf16x8 aF = *(const bf16x8*)(&h1[m16][kb]);
        bf16x8 bF[8];
        #pragma unroll
        for (int nt = 0; nt < 8; ++nt)
            bF[nt] = *(const bf16x8*)(fw2 + (size_t)(nt * 16 + m16) * F + kb);
        #pragma unroll
        for (int nt = 0; nt < 8; ++nt)
            acc[nt] = mfma_bf16(aF, bF[nt], acc[nt]);
    }

    // ---- stage 3: msg = y[src] * W, run-merged atomic scatter to agg[dst] ----
    int src[4], dst[4], ok[4];
    #pragma unroll
    for (int r = 0; r < 4; ++r) {
        const int s = s0 + q * 4 + r;
        const int sc = s < E ? s : E - 1;
        ok[r] = (s < E);
        src[r] = ssrc[sc];
        dst[r] = sdst[sc];
    }
    #pragma unroll
    for (int nt = 0; nt < 8; ++nt) {
        const int col = nt * 16 + m16;
        const float b = fb2[col];
        float yv[4];
        #pragma unroll
        for (int r = 0; r < 4; ++r)
            yv[r] = y[(size_t)src[r] * F + col];   // clamped src is valid
        float run = 0.f;
        #pragma unroll
        for (int r = 0; r < 4; ++r) {
            if (ok[r]) {
                const float wV = ssp(acc[nt][r] + b);
                run = fmaf(yv[r], wV, run);
                const bool flush = (r == 3) || (!ok[r + 1]) || (dst[r + 1] != dst[r]);
                if (flush) {
                    unsafeAtomicAdd(&agg[(size_t)dst[r] * F + col], run);
                    run = 0.f;
                }
            }
        }
    }
}

// ---------------------------------------------------------------------------
// out = ssp(agg @ s_w1.T) @ s_w2.T   (split bf16 both stages -> ~f32 exact)
// 32 rows/block, wave (g,c) quadrants; block-shared hh/hl for the transpose.
// ---------------------------------------------------------------------------
__global__ __launch_bounds__(256, 5) void state_kernel(
    const float* __restrict__ agg,
    const __bf16* __restrict__ w1h, const __bf16* __restrict__ w1l,
    const __bf16* __restrict__ w2h, const __bf16* __restrict__ w2l,
    float* __restrict__ out, int M)
{
    __shared__ __align__(16) __bf16 hh[32][136];
    __shared__ __align__(16) __bf16 hl[32][136];

    const int tid = threadIdx.x;
    const int wv = tid >> 6, lane = tid & 63;
    const int m16 = lane & 15, q = lane >> 4;
    const int g = wv & 1, c = wv >> 1;
    const int rowA0 = blockIdx.x * 32 + g * 16 + m16;
    const int rowA = rowA0 < M ? rowA0 : M - 1;

    // stage 1: h = ssp(agg @ s_w1.T), wave computes cols [64c, 64c+64)
    floatx4 acc[4] = {};
    #pragma unroll
    for (int ks = 0; ks < 4; ++ks) {
        const int kb = ks * 32 + q * 8;
        const float4* p = (const float4*)(agg + (size_t)rowA * F + kb);
        float4 a0 = p[0], a1 = p[1];
        float fv[8] = {a0.x, a0.y, a0.z, a0.w, a1.x, a1.y, a1.z, a1.w};
        bf16x8 ah, al;
        #pragma unroll
        for (int i = 0; i < 8; ++i) {
            __bf16 h = (__bf16)fv[i];
            ah[i] = h; al[i] = (__bf16)(fv[i] - (float)h);
        }
        bf16x8 bH[4], bL[4];
        #pragma unroll
        for (int nt = 0; nt < 4; ++nt) {
            const size_t wo = (size_t)(c * 64 + nt * 16 + m16) * F + kb;
            bH[nt] = *(const bf16x8*)(w1h + wo);
            bL[nt] = *(const bf16x8*)(w1l + wo);
        }
        #pragma unroll
        for (int nt = 0; nt < 4; ++nt) {
            acc[nt] = mfma_bf16(ah, bH[nt], acc[nt]);
            acc[nt] = mfma_bf16(al, bH[nt], acc[nt]);
            acc[nt] = mfma_bf16(ah, bL[nt], acc[nt]);
        }
    }
    #pragma unroll
    for (int nt = 0; nt < 4; ++nt) {
        const int col = c * 64 + nt * 16 + m16;
        #pragma unroll
        for (int r = 0; r < 4; ++r) {
            const int row = g * 16 + q * 4 + r;
            const float h = ssp(acc[nt][r]);
            const __bf16 H = (__bf16)h;
            hh[row][col] = H;
            hl[row][col] = (__bf16)(h - (float)H);
        }
    }
    __syncthreads();

    // stage 2: out = h @ s_w2.T over all 128 K-cols (written by both c-halves)
    floatx4 zero = {};
    #pragma unroll
    for (int nt = 0; nt < 4; ++nt) acc[nt] = zero;
    #pragma unroll
    for (int ks = 0; ks < 4; ++ks) {
        const int kb = ks * 32 + q * 8;
        bf16x8 aH = *(const bf16x8*)(&hh[g * 16 + m16][kb]);
        bf16x8 aL = *(const bf16x8*)(&hl[g * 16 + m16][kb]);
        bf16x8 bH[4], bL[4];
        #pragma unroll
        for (int nt = 0; nt < 4; ++nt) {
            const size_t wo = (size_t)(c * 64 + nt * 16 + m16) * F + kb;
            bH[nt] = *(const bf16x8*)(w2h + wo);
            bL[nt] = *(const bf16x8*)(w2l + wo);
        }
        #pragma unroll
        for (int nt = 0; nt < 4; ++nt) {
            acc[nt] = mfma_bf16(aH, bH[nt], acc[nt]);
            acc[nt] = mfma_bf16(aL, bH[nt], acc[nt]);
            acc[nt] = mfma_bf16(aH, bL[nt], acc[nt]);
        }
    }
    const int rowD0 = blockIdx.x * 32 + g * 16 + q * 4;
    #pragma unroll
    for (int nt = 0; nt < 4; ++nt) {
        const int col = c * 64 + nt * 16 + m16;
        #pragma unroll
        for (int r = 0; r < 4; ++r) {
            const int row = rowD0 + r;
            if (row < M) out[(size_t)row * F + col] = acc[nt][r];
        }
    }
}

// ---------------------------------------------------------------------------
extern "C" void kernel_launch(void* const* d_in, const int* in_sizes, int n_in,
                              void* d_out, int out_size, void* d_ws, size_t ws_size,
                              hipStream_t stream)
{
    const float* x         = (const float*)d_in[0];
    const float* edge_attr = (const float*)d_in[1];
    const int*   eidx      = (const int*)d_in[2];
    const float* fc1w      = (const float*)d_in[3];
    const float* fw1       = (const float*)d_in[4];
    const float* fb1       = (const float*)d_in[5];
    const float* fw2       = (const float*)d_in[6];
    const float* fb2       = (const float*)d_in[7];
    const float* sw1       = (const float*)d_in[8];
    const float* sw2       = (const float*)d_in[9];
    float* out = (float*)d_out;

    const int N = in_sizes[0] / F;     // 50000
    const int E = in_sizes[1] / F;     // 600000

    float* agg = (float*)d_ws;
    float* y   = agg + (size_t)N * F;
    __bf16* wb = (__bf16*)(y + (size_t)N * F);
    const int WSZ = F * F;
    __bf16* fc1h = wb;            __bf16* fc1l = wb + WSZ;
    __bf16* fw1h = wb + 2 * WSZ;  __bf16* fw2h = wb + 3 * WSZ;
    __bf16* sw1h = wb + 4 * WSZ;  __bf16* sw1l = wb + 5 * WSZ;
    __bf16* sw2h = wb + 6 * WSZ;  __bf16* sw2l = wb + 7 * WSZ;
    int* cnt   = (int*)(wb + 8 * WSZ);           // N: hist -> cursor
    int* bsums = cnt + N;                        // 64 scan block sums
    int* perm  = bsums + 64;                     // E: original edge per slot
    int* ssrc  = perm + E;                       // E: src per sorted slot
    int* sdst  = ssrc + E;                       // E: dst per sorted slot

    const int nb1 = (N + 1023) / 1024;

    hipMemsetAsync(agg, 0, (size_t)N * F * sizeof(float), stream);

    prep_kernel<<<(WSZ + 255) / 256, 256, 0, stream>>>(
        fc1w, fw1, fw2, sw1, sw2, fc1h, fc1l, fw1h, fw2h, sw1h, sw1l, sw2h, sw2l,
        cnt, N);

    fc1_kernel<<<(N + 31) / 32, 256, 0, stream>>>(x, fc1h, fc1l, y, N);

    // build dst-sorted edge order
    hist_kernel<<<(E + 255) / 256, 256, 0, stream>>>(eidx, cnt, E);
    scan1_kernel<<<nb1, 1024, 0, stream>>>(cnt, bsums, N);
    scan2_kernel<<<1, 64, 0, stream>>>(bsums, nb1);
    scan3_kernel<<<nb1, 1024, 0, stream>>>(cnt, bsums, N);
    scatter_kernel<<<(E + 255) / 256, 256, 0, stream>>>(eidx, cnt, perm, ssrc, sdst, E);

    // fused filter-MLP + gather + run-merged scatter
    edge_kernel<<<(E + 63) / 64, 256, 0, stream>>>(
        edge_attr, perm, ssrc, sdst, fb1, fb2, fw1h, fw2h, y, agg, E);

    state_kernel<<<(N + 31) / 32, 256, 0, stream>>>(
        agg, sw1h, sw1l, sw2h, sw2l, out, N);
}